// Round 1
// baseline (526.279 us; speedup 1.0000x reference)
//
#include <hip/hip_runtime.h>
#include <stdint.h>

#define ROWS   4096
#define NCOL   8192
#define TARGET 7680
#define NW     (NCOL - TARGET + 1)   // 513 windows
#define NT     256                   // threads per block

// Order-preserving float->uint key transform
__device__ __forceinline__ uint32_t f2k(uint32_t u) {
    return (u & 0x80000000u) ? ~u : (u | 0x80000000u);
}
__device__ __forceinline__ float k2f(uint32_t k) {
    uint32_t u = (k & 0x80000000u) ? (k & 0x7FFFFFFFu) : ~k;
    return __uint_as_float(u);
}

// Given hist[nbins], find bin containing rank k (0-indexed ascending) and the
// residual rank within that bin. nbins must be a multiple of NT.
// Writes result[0]=bin, result[1]=rank_within_bin. Ends with __syncthreads().
__device__ void find_bin(const uint32_t* hist, int nbins, uint32_t k,
                         uint32_t* seg, uint32_t* result, int tid) {
    const int bpt  = nbins >> 8;     // bins per thread
    const int base = tid * bpt;
    uint32_t ssum = 0;
    for (int j = 0; j < bpt; j++) ssum += hist[base + j];
    seg[tid] = ssum;
    __syncthreads();
    // Hillis-Steele inclusive scan over 256 segment sums
    for (int off = 1; off < NT; off <<= 1) {
        uint32_t add = (tid >= off) ? seg[tid - off] : 0u;
        __syncthreads();
        seg[tid] += add;
        __syncthreads();
    }
    uint32_t incl = seg[tid];
    uint32_t excl = incl - ssum;
    if (k >= excl && k < incl) {     // exactly one thread matches
        uint32_t c = excl;
        for (int j = 0; j < bpt; j++) {
            uint32_t h = hist[base + j];
            if (k < c + h) { result[0] = (uint32_t)(base + j); result[1] = k - c; break; }
            c += h;
        }
    }
    __syncthreads();
}

__global__ __launch_bounds__(NT)
void recall_window_kernel(const float* __restrict__ x, float* __restrict__ out) {
    __shared__ uint32_t keys[NCOL];      // 32 KB
    __shared__ uint32_t hist[2048];      // 8 KB
    __shared__ uint32_t seg[NT];         // 1 KB
    __shared__ uint32_t res[2];
    __shared__ uint32_t bot[1024];       // 4 KB
    __shared__ uint32_t topb[1024];      // 4 KB
    __shared__ uint32_t cnts[2];
    __shared__ float    rval[NT];
    __shared__ int      ridx[NT];

    const int tid = threadIdx.x;
    const int row = blockIdx.x;

    // ---- Load row, transform to sortable keys (vectorized 16B) ----
    const uint4* xv = (const uint4*)(x + (size_t)row * NCOL);
    uint4* kv = (uint4*)keys;
    for (int i = tid; i < NCOL / 4; i += NT) {
        uint4 v = xv[i];
        uint4 t;
        t.x = f2k(v.x); t.y = f2k(v.y); t.z = f2k(v.z); t.w = f2k(v.w);
        kv[i] = t;
    }
    for (int i = tid; i < 2048; i += NT) hist[i] = 0;
    __syncthreads();

    // ---- Level-1 histogram: top 11 bits (shared by both rank queries) ----
    for (int i = tid; i < NCOL; i += NT) atomicAdd(&hist[keys[i] >> 21], 1u);
    __syncthreads();

    find_bin(hist, 2048, NW - 1, seg, res, tid);        // rank 512
    uint32_t b1_lo = res[0], r1_lo = res[1];
    find_bin(hist, 2048, TARGET - 1, seg, res, tid);    // rank 7679
    uint32_t b1_hi = res[0], r1_hi = res[1];

    // ---- Refine K_lo: bits [20:10], then [9:0] ----
    for (int i = tid; i < 2048; i += NT) hist[i] = 0;
    __syncthreads();
    for (int i = tid; i < NCOL; i += NT) {
        uint32_t key = keys[i];
        if ((key >> 21) == b1_lo) atomicAdd(&hist[(key >> 10) & 0x7FFu], 1u);
    }
    __syncthreads();
    find_bin(hist, 2048, r1_lo, seg, res, tid);
    uint32_t pfx_lo = (b1_lo << 11) | res[0];
    uint32_t r2_lo  = res[1];

    for (int i = tid; i < 1024; i += NT) hist[i] = 0;
    __syncthreads();
    for (int i = tid; i < NCOL; i += NT) {
        uint32_t key = keys[i];
        if ((key >> 10) == pfx_lo) atomicAdd(&hist[key & 0x3FFu], 1u);
    }
    __syncthreads();
    find_bin(hist, 1024, r2_lo, seg, res, tid);
    uint32_t K_lo = (pfx_lo << 10) | res[0];

    // ---- Refine K_hi: bits [20:10], then [9:0] ----
    for (int i = tid; i < 2048; i += NT) hist[i] = 0;
    __syncthreads();
    for (int i = tid; i < NCOL; i += NT) {
        uint32_t key = keys[i];
        if ((key >> 21) == b1_hi) atomicAdd(&hist[(key >> 10) & 0x7FFu], 1u);
    }
    __syncthreads();
    find_bin(hist, 2048, r1_hi, seg, res, tid);
    uint32_t pfx_hi = (b1_hi << 11) | res[0];
    uint32_t r2_hi  = res[1];

    for (int i = tid; i < 1024; i += NT) hist[i] = 0;
    __syncthreads();
    for (int i = tid; i < NCOL; i += NT) {
        uint32_t key = keys[i];
        if ((key >> 10) == pfx_hi) atomicAdd(&hist[key & 0x3FFu], 1u);
    }
    __syncthreads();
    find_bin(hist, 1024, r2_hi, seg, res, tid);
    uint32_t K_hi = (pfx_hi << 10) | res[0];

    // ---- Collect strict outliers; fill remainder with threshold copies ----
    if (tid < 2) cnts[tid] = 0;
    __syncthreads();
    for (int i = tid; i < NCOL; i += NT) {
        uint32_t key = keys[i];
        if (key < K_lo) bot[atomicAdd(&cnts[0], 1u)]  = key;
        if (key > K_hi) topb[atomicAdd(&cnts[1], 1u)] = key;
    }
    __syncthreads();
    uint32_t cb = cnts[0], ct = cnts[1];
    // ranks [0,512]: cb elems < K_lo plus (513-cb) copies of K_lo; pad to 1024
    for (int i = (int)cb + tid; i < 1024; i += NT) bot[i]  = (i < NW) ? K_lo : 0xFFFFFFFFu;
    // ranks [7679,8191]: (513-ct) copies of K_hi plus ct elems > K_hi; pad
    for (int i = (int)ct + tid; i < 1024; i += NT) topb[i] = (i < NW) ? K_hi : 0xFFFFFFFFu;

    // ---- Bitonic sort both 1024-element buffers (ascending) ----
    for (int k = 2; k <= 1024; k <<= 1) {
        for (int j = k >> 1; j > 0; j >>= 1) {
            __syncthreads();
            const int jm1 = j - 1;
            for (int p = tid; p < 1024; p += NT) {
                uint32_t* a = (p >> 9) ? topb : bot;
                int q = p & 511;
                int i = ((q & ~jm1) << 1) | (q & jm1);
                int l = i + j;
                bool asc = ((i & k) == 0);
                uint32_t vi = a[i], vl = a[l];
                bool sw = asc ? (vi > vl) : (vi < vl);
                if (sw) { a[i] = vl; a[l] = vi; }
            }
        }
    }
    __syncthreads();

    // ---- lengths + first-occurrence argmin ----
    float lbest = __int_as_float(0x7F800000);  // +inf
    int   lidx  = 0x7FFFFFFF;
    for (int i = tid; i < NW; i += NT) {
        float len = k2f(topb[i]) - k2f(bot[i]);
        if (len < lbest) { lbest = len; lidx = i; }
    }
    rval[tid] = lbest; ridx[tid] = lidx;
    __syncthreads();
    for (int off = NT / 2; off > 0; off >>= 1) {
        if (tid < off) {
            float v2 = rval[tid + off]; int i2 = ridx[tid + off];
            float v1 = rval[tid];       int i1 = ridx[tid];
            if (v2 < v1 || (v2 == v1 && i2 < i1)) { rval[tid] = v2; ridx[tid] = i2; }
        }
        __syncthreads();
    }
    if (tid == 0) {
        int idx = ridx[0];
        out[row]        = k2f(bot[idx]);    // left  = s[idx]
        out[ROWS + row] = k2f(topb[idx]);   // right = s[idx + target - 1]
    }
}

extern "C" void kernel_launch(void* const* d_in, const int* in_sizes, int n_in,
                              void* d_out, int out_size, void* d_ws, size_t ws_size,
                              hipStream_t stream) {
    const float* x = (const float*)d_in[0];
    float* out = (float*)d_out;
    recall_window_kernel<<<ROWS, NT, 0, stream>>>(x, out);
}

// Round 2
// 318.906 us; speedup vs baseline: 1.6503x; 1.6503x over previous
//
#include <hip/hip_runtime.h>
#include <stdint.h>

#define ROWS   4096
#define NCOL   8192
#define TARGET 7680
#define NW     (NCOL - TARGET + 1)   // 513 windows
#define NT     256                   // threads per block
#define VPT    (NCOL / NT)           // 32 values per thread (held in VGPRs)

// Order-preserving float->uint key transform
__device__ __forceinline__ uint32_t f2k(uint32_t u) {
    return (u & 0x80000000u) ? ~u : (u | 0x80000000u);
}
__device__ __forceinline__ float k2f(uint32_t k) {
    uint32_t u = (k & 0x80000000u) ? (k & 0x7FFFFFFFu) : ~k;
    return __uint_as_float(u);
}

struct Smem {
    uint32_t hist[2048];   // 8 KB  (shared lo/hi halves in refinement levels)
    uint32_t bot[1024];    // 4 KB
    uint32_t topb[1024];   // 4 KB
    uint32_t wsum[8];
    uint32_t res[4];
    uint32_t cnts[4];      // [0],[1]: L4 bit counts; [2],[3]: collect counters
    float    rv[4];
    int      ri[4];
};

// Scan hist[2048] (8 bins/thread, wave-shuffle scan, 3 barriers) and locate
// ranks ka and kb. If split: ka is a rank within bins [0,1024) and kb a rank
// within bins [1024,2048) (kb adjusted by the first-half total).
// Out: res[0]=bin_a res[1]=rank_in_bin_a res[2]=bin_b res[3]=rank_in_bin_b.
__device__ void scan_locate(Smem& sm, uint32_t ka, uint32_t kb, bool split, int tid) {
    const int lane = tid & 63, wid = tid >> 6;
    const int base = tid * 8;
    uint32_t h[8]; uint32_t s0 = 0;
    #pragma unroll
    for (int j = 0; j < 8; j++) { h[j] = sm.hist[base + j]; s0 += h[j]; }
    // wave-level inclusive scan of per-thread sums
    uint32_t sc = s0;
    #pragma unroll
    for (int off = 1; off < 64; off <<= 1) {
        uint32_t n = __shfl_up(sc, off, 64);
        if (lane >= off) sc += n;
    }
    if (lane == 63) sm.wsum[wid] = sc;
    __syncthreads();
    uint32_t woff = 0;
    for (int w = 0; w < wid; w++) woff += sm.wsum[w];
    uint32_t incl = sc + woff;
    uint32_t excl = incl - s0;
    if (split && tid == 127) sm.wsum[4] = incl;  // total of first half
    __syncthreads();
    uint32_t kb2 = split ? kb + sm.wsum[4] : kb;
    if (ka >= excl && ka < incl) {
        uint32_t c = excl; bool done = false;
        #pragma unroll
        for (int j = 0; j < 8; j++) {
            if (!done) {
                if (ka < c + h[j]) { sm.res[0] = (uint32_t)(base + j); sm.res[1] = ka - c; done = true; }
                else c += h[j];
            }
        }
    }
    if (kb2 >= excl && kb2 < incl) {
        uint32_t c = excl; bool done = false;
        #pragma unroll
        for (int j = 0; j < 8; j++) {
            if (!done) {
                if (kb2 < c + h[j]) { sm.res[2] = (uint32_t)(base + j); sm.res[3] = kb2 - c; done = true; }
                else c += h[j];
            }
        }
    }
    __syncthreads();
}

__global__ __launch_bounds__(NT, 4)
void recall_window_kernel(const float* __restrict__ x, float* __restrict__ out) {
    __shared__ Smem sm;
    const int tid = threadIdx.x;
    const int row = blockIdx.x;

    // ---- Load entire row into registers (coalesced 16B loads) ----
    uint32_t v[VPT];
    const uint4* xv = (const uint4*)(x + (size_t)row * NCOL);
    #pragma unroll
    for (int j = 0; j < VPT / 4; j++) {
        uint4 t = xv[tid + j * NT];
        v[4 * j + 0] = f2k(t.x);
        v[4 * j + 1] = f2k(t.y);
        v[4 * j + 2] = f2k(t.z);
        v[4 * j + 3] = f2k(t.w);
    }

    // ---- zero hist + counters ----
    #pragma unroll
    for (int j = 0; j < 8; j++) sm.hist[tid + j * NT] = 0;
    if (tid < 4) sm.cnts[tid] = 0;
    __syncthreads();

    // ---- L1: top 11 bits [31:21], one hist shared by both ranks ----
    #pragma unroll
    for (int j = 0; j < VPT; j++) atomicAdd(&sm.hist[v[j] >> 21], 1u);
    __syncthreads();
    scan_locate(sm, NW - 1, TARGET - 1, false, tid);   // ranks 512 and 7679
    uint32_t b1_lo = sm.res[0], r1_lo = sm.res[1];
    uint32_t b1_hi = sm.res[2], r1_hi = sm.res[3];

    // ---- L2: bits [20:11]; lo in bins [0,1024), hi in [1024,2048) ----
    #pragma unroll
    for (int j = 0; j < 8; j++) sm.hist[tid + j * NT] = 0;
    __syncthreads();
    #pragma unroll
    for (int j = 0; j < VPT; j++) {
        uint32_t k = v[j];
        uint32_t top11 = k >> 21;
        uint32_t d = (k >> 11) & 1023u;
        if (top11 == b1_lo) atomicAdd(&sm.hist[d], 1u);
        if (top11 == b1_hi) atomicAdd(&sm.hist[1024u + d], 1u);
    }
    __syncthreads();
    scan_locate(sm, r1_lo, r1_hi, true, tid);
    uint32_t pfx21_lo = (b1_lo << 10) | (sm.res[0] & 1023u);
    uint32_t r2_lo    = sm.res[1];
    uint32_t pfx21_hi = (b1_hi << 10) | (sm.res[2] & 1023u);
    uint32_t r2_hi    = sm.res[3];

    // ---- L3: bits [10:1]; shared halves again ----
    #pragma unroll
    for (int j = 0; j < 8; j++) sm.hist[tid + j * NT] = 0;
    __syncthreads();
    #pragma unroll
    for (int j = 0; j < VPT; j++) {
        uint32_t k = v[j];
        uint32_t p21 = k >> 11;
        uint32_t d = (k >> 1) & 1023u;
        if (p21 == pfx21_lo) atomicAdd(&sm.hist[d], 1u);
        if (p21 == pfx21_hi) atomicAdd(&sm.hist[1024u + d], 1u);
    }
    __syncthreads();
    scan_locate(sm, r2_lo, r2_hi, true, tid);
    uint32_t pfx31_lo = (pfx21_lo << 10) | (sm.res[0] & 1023u);
    uint32_t r3_lo    = sm.res[1];
    uint32_t pfx31_hi = (pfx21_hi << 10) | (sm.res[2] & 1023u);
    uint32_t r3_hi    = sm.res[3];

    // ---- L4: final bit [0] via two block counters ----
    {
        uint32_t c0 = 0, c1 = 0;
        #pragma unroll
        for (int j = 0; j < VPT; j++) {
            uint32_t k = v[j];
            c0 += (uint32_t)(((k >> 1) == pfx31_lo) & ((k & 1u) == 0u));
            c1 += (uint32_t)(((k >> 1) == pfx31_hi) & ((k & 1u) == 0u));
        }
        if (c0) atomicAdd(&sm.cnts[0], c0);
        if (c1) atomicAdd(&sm.cnts[1], c1);
    }
    __syncthreads();
    uint32_t K_lo = (pfx31_lo << 1) | (r3_lo >= sm.cnts[0] ? 1u : 0u);
    uint32_t K_hi = (pfx31_hi << 1) | (r3_hi >= sm.cnts[1] ? 1u : 0u);

    // ---- Collect strict outliers from registers ----
    #pragma unroll
    for (int j = 0; j < VPT; j++) {
        uint32_t k = v[j];
        if (k < K_lo) sm.bot[atomicAdd(&sm.cnts[2], 1u)]  = k;
        if (k > K_hi) sm.topb[atomicAdd(&sm.cnts[3], 1u)] = k;
    }
    __syncthreads();
    uint32_t cb = sm.cnts[2], ct = sm.cnts[3];
    // bot: cb elems < K_lo, fill to 513 with K_lo copies, pad to 1024 with MAX
    for (int i = (int)cb + tid; i < 1024; i += NT) sm.bot[i]  = (i < NW) ? K_lo : 0xFFFFFFFFu;
    // top: ct elems > K_hi, fill to 513 with K_hi copies, pad to 1024 with MAX
    for (int i = (int)ct + tid; i < 1024; i += NT) sm.topb[i] = (i < NW) ? K_hi : 0xFFFFFFFFu;

    // ---- Bitonic sort both 1024-element buffers ascending ----
    for (int k = 2; k <= 1024; k <<= 1) {
        for (int j = k >> 1; j > 0; j >>= 1) {
            __syncthreads();
            const int jm1 = j - 1;
            #pragma unroll
            for (int pp = 0; pp < 4; pp++) {
                int p = tid + pp * NT;
                uint32_t* a = (p >> 9) ? sm.topb : sm.bot;
                int q = p & 511;
                int i = ((q & ~jm1) << 1) | (q & jm1);
                int l = i + j;
                bool asc = ((i & k) == 0);
                uint32_t vi = a[i], vl = a[l];
                bool sw = asc ? (vi > vl) : (vi < vl);
                if (sw) { a[i] = vl; a[l] = vi; }
            }
        }
    }
    __syncthreads();

    // ---- lengths + first-occurrence argmin (wave shuffle reduce) ----
    float lbest = __int_as_float(0x7F800000);  // +inf
    int   lidx  = 0x7FFFFFFF;
    for (int i = tid; i < NW; i += NT) {
        float len = k2f(sm.topb[i]) - k2f(sm.bot[i]);
        if (len < lbest) { lbest = len; lidx = i; }
    }
    const int lane = tid & 63, wid = tid >> 6;
    #pragma unroll
    for (int off = 32; off > 0; off >>= 1) {
        float v2 = __shfl_down(lbest, off, 64);
        int   i2 = __shfl_down(lidx,  off, 64);
        if (v2 < lbest || (v2 == lbest && i2 < lidx)) { lbest = v2; lidx = i2; }
    }
    if (lane == 0) { sm.rv[wid] = lbest; sm.ri[wid] = lidx; }
    __syncthreads();
    if (tid == 0) {
        float bv = sm.rv[0]; int bi = sm.ri[0];
        #pragma unroll
        for (int w = 1; w < 4; w++) {
            float v2 = sm.rv[w]; int i2 = sm.ri[w];
            if (v2 < bv || (v2 == bv && i2 < bi)) { bv = v2; bi = i2; }
        }
        out[row]        = k2f(sm.bot[bi]);    // left  = s[idx]
        out[ROWS + row] = k2f(sm.topb[bi]);   // right = s[idx + target - 1]
    }
}

extern "C" void kernel_launch(void* const* d_in, const int* in_sizes, int n_in,
                              void* d_out, int out_size, void* d_ws, size_t ws_size,
                              hipStream_t stream) {
    const float* x = (const float*)d_in[0];
    float* out = (float*)d_out;
    recall_window_kernel<<<ROWS, NT, 0, stream>>>(x, out);
}

// Round 3
// 223.047 us; speedup vs baseline: 2.3595x; 1.4298x over previous
//
#include <hip/hip_runtime.h>
#include <stdint.h>

#define ROWS   4096
#define NCOL   8192
#define TARGET 7680
#define NW     (NCOL - TARGET + 1)   // 513 windows
#define NT     256                   // threads per block
#define VPT    (NCOL / NT)           // 32 values per thread (in VGPRs)
#define NB     2048                  // level-1 select bins
#define NSB    1024                  // sub-bins per side (bot / top)
#define SCAP   3072                  // sorted-buffer capacity
#define MAXS   (SCAP / NT)           // max slots per thread in fixup (12)

struct Smem {
    uint32_t hist[NB];      // 8 KB: L1 hist, then sub-hist -> offsets -> incl
    float    sorted[SCAP];  // 12 KB: [0,cb) = bottom candidates, [cb,tot) = top
    uint32_t wsum[8];
    uint32_t res[4];        // locate2 out: [0]=B_lo [2]=B_hi
    uint32_t aux[2];        // [0]=cb (bot count), [1]=tot (cb+ct)
    float    fmin[4], fmax[4];
    float    rv[4];
    int      ri[4];
};

__device__ __forceinline__ int bin1f(float v, float mn, float s) {
    int b = (int)((v - mn) * s);
    return b < 0 ? 0 : (b > NB - 1 ? NB - 1 : b);
}
__device__ __forceinline__ int sbin_bot(float v, float mn, float sb) {
    int b = (int)((v - mn) * sb);
    return b < 0 ? 0 : (b > NSB - 1 ? NSB - 1 : b);
}
__device__ __forceinline__ int sbin_top(float v, float mx, float st) {
    int b = (int)((mx - v) * st);
    b = b < 0 ? 0 : (b > NSB - 1 ? NSB - 1 : b);
    return (NSB - 1) - b;
}

// Find bins containing ranks ka and kb in hist[NB] (non-destructive).
// Out: res[0]=bin(ka), res[2]=bin(kb). Ends with __syncthreads().
__device__ void locate2(Smem& sm, uint32_t ka, uint32_t kb, int tid) {
    const int lane = tid & 63, wid = tid >> 6;
    const int base = tid * 8;
    uint32_t h[8], s0 = 0;
    #pragma unroll
    for (int j = 0; j < 8; j++) { h[j] = sm.hist[base + j]; s0 += h[j]; }
    uint32_t sc = s0;
    #pragma unroll
    for (int off = 1; off < 64; off <<= 1) {
        uint32_t n = __shfl_up(sc, off, 64);
        if (lane >= off) sc += n;
    }
    if (lane == 63) sm.wsum[wid] = sc;
    __syncthreads();
    uint32_t woff = 0;
    for (int w = 0; w < wid; w++) woff += sm.wsum[w];
    uint32_t incl = sc + woff, excl = incl - s0;
    if (ka >= excl && ka < incl) {
        uint32_t c = excl; bool done = false;
        #pragma unroll
        for (int j = 0; j < 8; j++) {
            if (!done) {
                if (ka < c + h[j]) { sm.res[0] = (uint32_t)(base + j); done = true; }
                else c += h[j];
            }
        }
    }
    if (kb >= excl && kb < incl) {
        uint32_t c = excl; bool done = false;
        #pragma unroll
        for (int j = 0; j < 8; j++) {
            if (!done) {
                if (kb < c + h[j]) { sm.res[2] = (uint32_t)(base + j); done = true; }
                else c += h[j];
            }
        }
    }
    __syncthreads();
}

// In-place exclusive scan of hist[NB] -> per-bin scatter offsets.
// Exports aux[0] = prefix at bin NSB (bot total), aux[1] = grand total.
__device__ void scan_offsets(Smem& sm, int tid) {
    const int lane = tid & 63, wid = tid >> 6;
    const int base = tid * 8;
    uint32_t h[8], s0 = 0;
    #pragma unroll
    for (int j = 0; j < 8; j++) { h[j] = sm.hist[base + j]; s0 += h[j]; }
    uint32_t sc = s0;
    #pragma unroll
    for (int off = 1; off < 64; off <<= 1) {
        uint32_t n = __shfl_up(sc, off, 64);
        if (lane >= off) sc += n;
    }
    if (lane == 63) sm.wsum[wid] = sc;
    __syncthreads();
    uint32_t woff = 0;
    for (int w = 0; w < wid; w++) woff += sm.wsum[w];
    uint32_t run = sc - s0 + woff;       // thread-exclusive base
    if (tid == (NSB / 8)) sm.aux[0] = run;   // exclusive prefix at bin NSB = cb
    #pragma unroll
    for (int j = 0; j < 8; j++) { sm.hist[base + j] = run; run += h[j]; }
    if (tid == NT - 1) sm.aux[1] = run;      // grand total
    __syncthreads();
}

__global__ __launch_bounds__(NT, 4)
void recall_window_kernel(const float* __restrict__ x, float* __restrict__ out) {
    __shared__ Smem sm;
    const int tid = threadIdx.x;
    const int row = blockIdx.x;
    const int lane = tid & 63, wid = tid >> 6;

    // ---- Load row into registers (coalesced 16B) ----
    float v[VPT];
    const float4* xv = (const float4*)(x + (size_t)row * NCOL);
    #pragma unroll
    for (int j = 0; j < VPT / 4; j++) {
        float4 t = xv[tid + j * NT];
        v[4 * j + 0] = t.x; v[4 * j + 1] = t.y;
        v[4 * j + 2] = t.z; v[4 * j + 3] = t.w;
    }

    // ---- Block min/max ----
    float mn = v[0], mx = v[0];
    #pragma unroll
    for (int j = 1; j < VPT; j++) { mn = fminf(mn, v[j]); mx = fmaxf(mx, v[j]); }
    #pragma unroll
    for (int off = 32; off > 0; off >>= 1) {
        mn = fminf(mn, __shfl_down(mn, off, 64));
        mx = fmaxf(mx, __shfl_down(mx, off, 64));
    }
    if (lane == 0) { sm.fmin[wid] = mn; sm.fmax[wid] = mx; }
    #pragma unroll
    for (int j = 0; j < 8; j++) sm.hist[tid + j * NT] = 0;
    __syncthreads();
    mn = fminf(fminf(sm.fmin[0], sm.fmin[1]), fminf(sm.fmin[2], sm.fmin[3]));
    mx = fmaxf(fmaxf(sm.fmax[0], sm.fmax[1]), fmaxf(sm.fmax[2], sm.fmax[3]));

    if (!(mx > mn)) {   // all values equal (uniform branch)
        if (tid == 0) { out[row] = mn; out[ROWS + row] = mn; }
        return;
    }
    const float scale1 = (float)NB / (mx - mn);

    // ---- L1: value-linear histogram (low-collision atomics) ----
    #pragma unroll
    for (int j = 0; j < VPT; j++) atomicAdd(&sm.hist[bin1f(v[j], mn, scale1)], 1u);
    __syncthreads();
    locate2(sm, NW - 1, TARGET - 1, tid);   // bins of rank 512 / rank 7679
    const int B_lo = (int)sm.res[0];
    const int B_hi = (int)sm.res[2];

    // ---- Sub-histogram of candidates (bot -> bins [0,NSB), top -> [NSB,2*NSB)) ----
    #pragma unroll
    for (int j = 0; j < 8; j++) sm.hist[tid + j * NT] = 0;
    __syncthreads();
    const float scale_b = (float)NSB * scale1 / (float)(B_lo + 1);
    const float scale_t = (float)NSB * scale1 / (float)(NB - B_hi);
    #pragma unroll
    for (int j = 0; j < VPT; j++) {
        float val = v[j];
        int b1 = bin1f(val, mn, scale1);
        if (b1 <= B_lo)      atomicAdd(&sm.hist[sbin_bot(val, mn, scale_b)], 1u);
        else if (b1 >= B_hi) atomicAdd(&sm.hist[NSB + sbin_top(val, mx, scale_t)], 1u);
    }
    __syncthreads();
    scan_offsets(sm, tid);
    const uint32_t cb  = sm.aux[0];
    uint32_t tot = sm.aux[1]; if (tot > SCAP) tot = SCAP;

    // ---- Scatter to sorted slots (within-bin order arbitrary) ----
    #pragma unroll
    for (int j = 0; j < VPT; j++) {
        float val = v[j];
        int b1 = bin1f(val, mn, scale1);
        int gb = -1;
        if (b1 <= B_lo)      gb = sbin_bot(val, mn, scale_b);
        else if (b1 >= B_hi) gb = NSB + sbin_top(val, mx, scale_t);
        if (gb >= 0) {
            uint32_t pos = atomicAdd(&sm.hist[gb], 1u);
            if (pos < SCAP) sm.sorted[pos] = val;
        }
    }
    __syncthreads();
    // now hist[gb] = inclusive prefix; bin start = hist[gb-1] (or 0)

    // ---- Fix-up: order elements within multi-element bins ----
    int   tgt[MAXS];
    float fvv[MAXS];
    #pragma unroll
    for (int it = 0; it < MAXS; it++) {
        int s = tid + it * NT;
        tgt[it] = -1;
        if (s < (int)tot) {
            float vv = sm.sorted[s];
            int gb = (s < (int)cb) ? sbin_bot(vv, mn, scale_b)
                                   : (NSB + sbin_top(vv, mx, scale_t));
            uint32_t start = (gb == 0) ? 0u : sm.hist[gb - 1];
            uint32_t end   = sm.hist[gb];
            if (end > SCAP) end = SCAP;
            uint32_t r = 0;
            if (end - start > 1) {
                for (uint32_t q = start; q < end; q++) {
                    float u = sm.sorted[q];
                    r += (u < vv) || (u == vv && (int)q < s);
                }
            }
            tgt[it] = (int)(start + r);
            fvv[it] = vv;
        }
    }
    __syncthreads();
    #pragma unroll
    for (int it = 0; it < MAXS; it++)
        if (tgt[it] >= 0) sm.sorted[tgt[it]] = fvv[it];
    __syncthreads();

    // sorted[0..cb) = global ranks 0..cb-1 ascending;
    // sorted[cb..tot) = global ranks 8192-ct..8191 ascending (ct = tot-cb).
    // window i: left = rank i = sorted[i]; right = rank i+7679 = sorted[tot-513+i]

    // ---- lengths + first-occurrence argmin ----
    const int topstart = (int)tot - NW;
    float lbest = __int_as_float(0x7F800000);   // +inf
    int   lidx  = 0x7FFFFFFF;
    for (int i = tid; i < NW; i += NT) {
        float len = sm.sorted[topstart + i] - sm.sorted[i];
        if (len < lbest) { lbest = len; lidx = i; }
    }
    #pragma unroll
    for (int off = 32; off > 0; off >>= 1) {
        float v2 = __shfl_down(lbest, off, 64);
        int   i2 = __shfl_down(lidx,  off, 64);
        if (v2 < lbest || (v2 == lbest && i2 < lidx)) { lbest = v2; lidx = i2; }
    }
    if (lane == 0) { sm.rv[wid] = lbest; sm.ri[wid] = lidx; }
    __syncthreads();
    if (tid == 0) {
        float bv = sm.rv[0]; int bi = sm.ri[0];
        #pragma unroll
        for (int w = 1; w < 4; w++) {
            float v2 = sm.rv[w]; int i2 = sm.ri[w];
            if (v2 < bv || (v2 == bv && i2 < bi)) { bv = v2; bi = i2; }
        }
        out[row]        = sm.sorted[bi];             // left  = s[idx]
        out[ROWS + row] = sm.sorted[topstart + bi];  // right = s[idx+target-1]
    }
}

extern "C" void kernel_launch(void* const* d_in, const int* in_sizes, int n_in,
                              void* d_out, int out_size, void* d_ws, size_t ws_size,
                              hipStream_t stream) {
    const float* x = (const float*)d_in[0];
    float* out = (float*)d_out;
    recall_window_kernel<<<ROWS, NT, 0, stream>>>(x, out);
}